// Round 1
// 5552.656 us; speedup vs baseline: 1.1931x; 1.1931x over previous
//
#include <hip/hip_runtime.h>
#include <stdint.h>

#define Bn  128
#define En  1024
#define Kn  64
#define HDn 256
#define NGc 8    // batch groups of 16
#define NSc 16   // hidden slices of 16 dims

typedef short s8v __attribute__((ext_vector_type(8)));   // 8 x bf16 (bits)
typedef float f4v __attribute__((ext_vector_type(4)));

static __device__ __forceinline__ unsigned short f2bf(float f) {
  union { float f; unsigned u; } cv; cv.f = f;
  unsigned u = cv.u;
  unsigned r = u + 0x7fffu + ((u >> 16) & 1u);   // round-nearest-even
  return (unsigned short)(r >> 16);
}
static __device__ __forceinline__ float sigm(float x) {
  return 1.0f / (1.0f + __expf(-x));
}

// ---- prologue 1: detect mask storage format (1-byte bool vs 4-byte word) ----
__global__ void detect_mask_fmt(const uint8_t* __restrict__ m8, int* __restrict__ fmt) {
  const int b = blockIdx.x;
  const int e0 = threadIdx.x * 4;
  const uint8_t* row = m8 + (size_t)b * En;
  int bad = 0;
  uint8_t prev = row[e0];
  #pragma unroll
  for (int i = 1; i <= 4; ++i) {
    int e = e0 + i;
    if (e < En) {
      uint8_t cur = row[e];
      if (prev == 0 && cur != 0) bad = 1;
      prev = cur;
    }
  }
  if (threadIdx.x == 0 && row[0] == 0) bad = 1;
  if (bad) atomicOr(fmt, 1);
}

// ---- prologue 2: seq is one-hot -> recover event index via ballot ----
__global__ void compute_ev(const float* __restrict__ seq, int* __restrict__ ev) {
  const int idx  = blockIdx.x * 4 + (threadIdx.x >> 6);  // flat (b*En + t)
  const int lane = threadIdx.x & 63;
  float v = seq[(size_t)idx * Kn + lane];
  unsigned long long m = __ballot(v > 0.5f);
  if (lane == 0) ev[idx] = __ffsll((long long)m) - 1;
}

// ---- main: persistent single-wave WGs, V-slice in registers ----
// Sync redesign: h is published with RELAXED agent-scope atomic dword stores
// (global_store sc0 sc1 -> MALL, the device coherence point), ordered before a
// RELAXED flag fetch_add by a bare `s_waitcnt vmcnt(0)`. Readers poll with
// RELAXED atomic loads and read h with RELAXED atomic dword loads. This is the
// acquire/release publication pattern MINUS buffer_wbl2/buffer_inv (full L2
// writeback/invalidate per step), which were only needed for non-coherent
// plain accesses and dominated the 14.6k-cycle step time.
__global__ __launch_bounds__(64, 1) void ct_main(
    const float* __restrict__ times, const uint8_t* __restrict__ mask8,
    const float* __restrict__ U_w,  const float* __restrict__ U_b,
    const float* __restrict__ V_w,  const float* __restrict__ V_b,
    const float* __restrict__ Lw,   const float* __restrict__ scale,
    const int* __restrict__ ev,     unsigned short* __restrict__ h_buf,
    int* __restrict__ ctr,          const int* __restrict__ fmtp,
    float* __restrict__ out_lam, float* __restrict__ out_cl,
    float* __restrict__ out_cb,  float* __restrict__ out_dl,
    float* __restrict__ out_og)
{
  // U columns, transposed for per-event gather: U_lds[(k*16+dl)*12 + gate]
  __shared__ float U_lds[64 * 16 * 12];   // 48 KB

  const int lane = threadIdx.x;
  const int col  = lane & 15;       // B/C column: dim for gate tiles, batch for A
  const int quad = lane >> 4;
  const int g    = blockIdx.x >> 4; // batch group
  const int s    = blockIdx.x & 15; // hidden slice
  const int d0   = s * 16;
  const int fmt  = *fmtp;

  // ---- init LDS U (zero pad word 7..11, then fill) ----
  #pragma unroll 1
  for (int i = lane; i < 64 * 16 * 12; i += 64) U_lds[i] = 0.0f;
  #pragma unroll 1
  for (int i = lane; i < 7 * 16 * 64; i += 64) {
    int k = i & 63, dl = (i >> 6) & 15, g7 = i >> 10;
    U_lds[(k * 16 + dl) * 12 + g7] = U_w[(size_t)(g7 * HDn + d0 + dl) * Kn + k];
  }
  __syncthreads();

  // ---- V-slice B-fragments pinned in registers (bf16) ----
  // B-operand layout: lane holds B[n=lane&15][k = kc*32 + quad*8 + j], j=0..7
  s8v Bv[7][8];
  #pragma unroll
  for (int g7 = 0; g7 < 7; ++g7) {
    const float* src = V_w + (size_t)(g7 * HDn + d0 + col) * HDn;
    #pragma unroll
    for (int kc = 0; kc < 8; ++kc) {
      const float* p = src + kc * 32 + quad * 8;
      f4v a = *(const f4v*)(p);
      f4v b = *(const f4v*)(p + 4);
      s8v fr;
      fr[0] = (short)f2bf(a[0]); fr[1] = (short)f2bf(a[1]);
      fr[2] = (short)f2bf(a[2]); fr[3] = (short)f2bf(a[3]);
      fr[4] = (short)f2bf(b[0]); fr[5] = (short)f2bf(b[1]);
      fr[6] = (short)f2bf(b[2]); fr[7] = (short)f2bf(b[3]);
      Bv[g7][kc] = fr;
    }
  }
  // lambda tile: cols 0..3 hold Lw rows [4s,4s+4), rest zero
  s8v BL[8];
  const int kkc = s * 4 + col;
  {
    const bool lv = (col < 4);
    const float* src = Lw + (size_t)(lv ? kkc : 0) * HDn;
    #pragma unroll
    for (int kc = 0; kc < 8; ++kc) {
      const float* p = src + kc * 32 + quad * 8;
      s8v fr;
      #pragma unroll
      for (int j = 0; j < 8; ++j) fr[j] = lv ? (short)f2bf(p[j]) : (short)0;
      BL[kc] = fr;
    }
  }
  float bias[7];
  #pragma unroll
  for (int g7 = 0; g7 < 7; ++g7) {
    int j = g7 * HDn + d0 + col;
    bias[g7] = U_b[j] + V_b[j];
  }
  const float sc = scale[(kkc < Kn) ? kkc : 0];

  unsigned int* hbuf32 = (unsigned int*)h_buf;

  float c[4]  = {0, 0, 0, 0}, cb[4] = {0, 0, 0, 0};
  float hreg[4] = {0, 0, 0, 0}, pm[4] = {0, 0, 0, 0};
  int* my_ctr = ctr + g * 32;   // 128B-padded counter per group

  #pragma unroll 1
  for (int t = 0; t <= En; ++t) {
    const bool has_main = (t < En);

    // per-step scalar loads (independent of h -> issued before polling)
    int evv[4]; float dtv[4], mk[4];
    f4v u0v[4], u1v[4];
    if (has_main) {
      #pragma unroll
      for (int r = 0; r < 4; ++r) {
        const int bglob = g * 16 + quad * 4 + r;
        evv[r] = ev[(size_t)bglob * En + t];
        const float* tp = times + (size_t)bglob * (En + 1) + t;
        dtv[r] = tp[1] - tp[0];
        int mraw;
        if (fmt) mraw = ((const int*)mask8)[(size_t)bglob * En + t];
        else     mraw = (int)mask8[(size_t)bglob * En + t];
        mk[r] = (mraw != 0) ? 1.0f : 0.0f;
      }
      // U gather for this step's events: ds_read latency hides under the spin
      #pragma unroll
      for (int r = 0; r < 4; ++r) {
        const float* up = U_lds + ((size_t)evv[r] * 16 + col) * 12;
        u0v[r] = *(const f4v*)(up);
        u1v[r] = *(const f4v*)(up + 4);
      }
    }

    // lambda mask from the PREVIOUS step (epilogue moved after publish)
    float pmo[4];
    #pragma unroll
    for (int r = 0; r < 4; ++r) pmo[r] = pm[r];

    // wait for all 16 slice-WGs of the group to have published step t-1
    if (t > 0) {
      const int target = NSc * t;
      if (lane == 0) {
        while (__hip_atomic_load(my_ctr, __ATOMIC_RELAXED,
                                 __HIP_MEMORY_SCOPE_AGENT) < target) {
          __builtin_amdgcn_s_sleep(1);
        }
      }
      // pin subsequent coherent h-loads below the observed flag (rule #18)
      __builtin_amdgcn_sched_barrier(0);
      asm volatile("" ::: "memory");
    }

    // A-fragments: full h of the group, coherent dword loads from MALL.
    // A layout: lane holds A[m=lane&15][k = kc*32 + quad*8 + j]
    const int par = t & 1;
    const unsigned int* hb32 = hbuf32 + (size_t)(par * NGc + g) * 2048;
    s8v A[8];
    #pragma unroll
    for (int kc = 0; kc < 8; ++kc) {
      const int base = (kc * 2 + (quad >> 1)) * 128 + col * 8 + (quad & 1) * 4;
      union { unsigned int u[4]; s8v v; } cvt;
      #pragma unroll
      for (int j = 0; j < 4; ++j)
        cvt.u[j] = __hip_atomic_load(hb32 + base + j, __ATOMIC_RELAXED,
                                     __HIP_MEMORY_SCOPE_AGENT);
      A[kc] = cvt.v;
    }

    f4v acc[7] = {}; f4v accL = {0.0f, 0.0f, 0.0f, 0.0f};
    if (has_main) {
      // gates first: their results gate the h-publish (critical path);
      // lambda MFMAs issue after and overlap the gate epilogue.
      #pragma unroll
      for (int kc = 0; kc < 8; ++kc) {
        #pragma unroll
        for (int g7 = 0; g7 < 7; ++g7)
          acc[g7] = __builtin_amdgcn_mfma_f32_16x16x32_bf16(A[kc], Bv[g7][kc], acc[g7], 0, 0, 0);
      }
    }
    #pragma unroll
    for (int kc = 0; kc < 8; ++kc)
      accL = __builtin_amdgcn_mfma_f32_16x16x32_bf16(A[kc], BL[kc], accL, 0, 0, 0);

    float clv[4], cbv[4], dlv[4], ogv[4];
    if (has_main) {
      #pragma unroll
      for (int r = 0; r < 4; ++r) {
        float nn0 = acc[0][r] + u0v[r][0] + bias[0];
        float nn1 = acc[1][r] + u0v[r][1] + bias[1];
        float nn2 = acc[2][r] + u0v[r][2] + bias[2];
        float nn3 = acc[3][r] + u0v[r][3] + bias[3];
        float nn4 = acc[4][r] + u1v[r][0] + bias[4];
        float nn5 = acc[5][r] + u1v[r][1] + bias[5];
        float nn6 = acc[6][r] + u1v[r][2] + bias[6];
        float i_ = sigm(nn0), f_ = sigm(nn1);
        float ib = sigm(nn2), fb = sigm(nn3);
        float z_ = 2.0f * sigm(nn4), o_ = sigm(nn5);
        float dl = __logf(1.0f + __expf(nn6));          // softplus
        float clow = f_ * c[r] + i_ * z_;
        float cbn  = fb * cb[r] + ib * z_;
        float ed   = __expf(-dtv[r] * dl);
        float cn   = cbn + (clow - cbn) * ed;
        float hn   = o_ * (2.0f * sigm(2.0f * cn) - 1.0f);
        const bool mb = (mk[r] != 0.0f);
        c[r]    = mb ? cn  : c[r];
        cb[r]   = mb ? cbn : cb[r];
        hreg[r] = mb ? hn  : hreg[r];
        pm[r]   = mk[r];
        clv[r] = mb ? clow : 0.0f;
        cbv[r] = mb ? cbn  : 0.0f;
        dlv[r] = mb ? dl   : 0.0f;
        ogv[r] = mb ? o_   : 0.0f;
      }

      // ---- publish h slice via coherent dword stores, then relaxed flag ----
      // pack (col, col^1) bf16 pairs into dwords via neighbor exchange;
      // even cols store rows {0,1} of their quad, odd cols rows {2,3}.
      const int par2 = (t + 1) & 1;
      unsigned int* hw32 = hbuf32 + (size_t)(par2 * NGc + g) * 2048 + s * 128;
      float hsw[4];
      #pragma unroll
      for (int r = 0; r < 4; ++r) hsw[r] = __shfl_xor(hreg[r], 1, 64);
      const int evn = (col & 1);                 // 0 = even col, 1 = odd col
      unsigned int w[4];
      #pragma unroll
      for (int r = 0; r < 4; ++r) {
        unsigned int a  = f2bf(hreg[r]);
        unsigned int bn = f2bf(hsw[r]);
        // dword value is lane-parity independent: low = even col, high = odd
        w[r] = evn ? (bn | (a << 16)) : (a | (bn << 16));
      }
      const unsigned int wa = evn ? w[2] : w[0];
      const unsigned int wb = evn ? w[3] : w[1];
      const int ra = evn ? 2 : 0;                // runtime, used in address only
      __hip_atomic_store(hw32 + (quad * 4 + ra) * 8 + (col >> 1), wa,
                         __ATOMIC_RELAXED, __HIP_MEMORY_SCOPE_AGENT);
      __hip_atomic_store(hw32 + (quad * 4 + ra + 1) * 8 + (col >> 1), wb,
                         __ATOMIC_RELAXED, __HIP_MEMORY_SCOPE_AGENT);
      // order: h stores complete at the coherence point before the flag add.
      // vmcnt retires in issue order; A-loads already retired -> waits only
      // the 2 h stores. No buffer_wbl2, no L2 writeback.
      asm volatile("s_waitcnt vmcnt(0)" ::: "memory");
      if (lane == 0)
        __hip_atomic_fetch_add(my_ctr, 1, __ATOMIC_RELAXED,
                               __HIP_MEMORY_SCOPE_AGENT);
    }

    // lambda epilogue for step t-1 — off the critical path (after flag add)
    if (t > 0 && col < 4) {
      #pragma unroll
      for (int r = 0; r < 4; ++r) {
        const int bglob = g * 16 + quad * 4 + r;
        float q   = accL[r] / sc;
        float lam = sc * __logf(1.0f + __expf(q));
        __builtin_nontemporal_store((pmo[r] != 0.0f) ? lam : 0.0f,
            &out_lam[((size_t)bglob * En + (t - 1)) * Kn + kkc]);
      }
    }

    // bulk output stores (drain during next step's spin); nontemporal to
    // keep L2 warm for ev/times/mask
    if (has_main) {
      #pragma unroll
      for (int r = 0; r < 4; ++r) {
        const size_t off =
            ((size_t)(g * 16 + quad * 4 + r) * En + t) * HDn + d0 + col;
        __builtin_nontemporal_store(clv[r], &out_cl[off]);
        __builtin_nontemporal_store(cbv[r], &out_cb[off]);
        __builtin_nontemporal_store(dlv[r], &out_dl[off]);
        __builtin_nontemporal_store(ogv[r], &out_og[off]);
      }
    }
  }
}

extern "C" void kernel_launch(void* const* d_in, const int* in_sizes, int n_in,
                              void* d_out, int out_size, void* d_ws, size_t ws_size,
                              hipStream_t stream) {
  const float*   seq   = (const float*)d_in[0];
  const uint8_t* mask  = (const uint8_t*)d_in[1];
  const float*   times = (const float*)d_in[2];
  const float*   U_w   = (const float*)d_in[3];
  const float*   U_b   = (const float*)d_in[4];
  const float*   V_w   = (const float*)d_in[5];
  const float*   V_b   = (const float*)d_in[6];
  const float*   Lw    = (const float*)d_in[7];
  const float*   scale = (const float*)d_in[8];

  char* ws = (char*)d_ws;
  unsigned short* h_buf = (unsigned short*)ws;        // 131072 B (2 x 8 x 16 x 16 x 16 bf16)
  int* ctr = (int*)(ws + 131072);                     // 8 groups x 128 B
  int* fmt = (int*)(ws + 132096);                     // 128 B
  int* ev  = (int*)(ws + 132224);                     // 128*1024 ints

  // zero h-ping-pong buffers, counters, fmt flag (ev is fully overwritten)
  hipMemsetAsync(d_ws, 0, 132224, stream);

  detect_mask_fmt<<<dim3(Bn), dim3(256), 0, stream>>>(mask, fmt);
  compute_ev<<<dim3(Bn * En / 4), dim3(256), 0, stream>>>(seq, ev);

  float* out = (float*)d_out;
  float* out_lam = out;
  float* out_cl  = out_lam + (size_t)Bn * En * Kn;
  float* out_cb  = out_cl  + (size_t)Bn * En * HDn;
  float* out_dl  = out_cb  + (size_t)Bn * En * HDn;
  float* out_og  = out_dl  + (size_t)Bn * En * HDn;

  ct_main<<<dim3(NGc * NSc), dim3(64), 0, stream>>>(
      times, mask, U_w, U_b, V_w, V_b, Lw, scale,
      ev, h_buf, ctr, fmt, out_lam, out_cl, out_cb, out_dl, out_og);
}